// Round 11
// baseline (115.174 us; speedup 1.0000x reference)
//
#include <hip/hip_runtime.h>
#include <hip/hip_fp16.h>
#include <math.h>

// Problem constants (match reference)
#define BB 4096
#define LL 128
#define DD 64
#define VV 50257
#define TAB_ELEMS (VV * DD)   // 3,216,448 per table

typedef _Float16 h2_t __attribute__((ext_vector_type(2)));

// fp16x2 dot-accumulate: one v_dot2_f32_f16 where available.
__device__ __forceinline__ float dot2acc(unsigned a, unsigned b, float c) {
#if __has_builtin(__builtin_amdgcn_fdot2)
    return __builtin_amdgcn_fdot2(__builtin_bit_cast(h2_t, a),
                                  __builtin_bit_cast(h2_t, b), c, false);
#else
    const float2 fa = __half22float2(*(const __half2*)&a);
    const float2 fb = __half22float2(*(const __half2*)&b);
    return fmaf(fa.x, fb.x, fmaf(fa.y, fb.y, c));
#endif
}

__device__ __forceinline__ float2 cvt2(unsigned raw) {
    return __half22float2(*(const __half2*)&raw);
}

__device__ __forceinline__ unsigned pack_h2(float a, float b) {
    union { __half2 h; unsigned u; } p;
    p.h = __floats2half2_rn(a, b);
    return p.u;
}

// ---------------------------------------------------------------------------
// Kernel 1: stream-convert both fp32 tables to fp16 in workspace.
// ---------------------------------------------------------------------------
__global__ __launch_bounds__(256) void convert_tables_kernel(
    const float* __restrict__ mu, const float* __restrict__ feat,
    __half* __restrict__ out_mu, __half* __restrict__ out_feat)
{
    const int n4 = TAB_ELEMS / 4;
    for (int i = blockIdx.x * blockDim.x + threadIdx.x; i < n4;
         i += gridDim.x * blockDim.x) {
        const float4 m = ((const float4*)mu)[i];
        const float4 f = ((const float4*)feat)[i];
        uint2 pm, pf;
        pm.x = pack_h2(m.x, m.y); pm.y = pack_h2(m.z, m.w);
        pf.x = pack_h2(f.x, f.y); pf.y = pack_h2(f.z, f.w);
        ((uint2*)out_mu)[i]   = pm;
        ((uint2*)out_feat)[i] = pf;
    }
}

// ---------------------------------------------------------------------------
// Kernel 2: R10 skeleton with (1) feat gathers mask-skipped via the kept
// bitmask, (2) barriers 7 -> 5: q rebuilt per-lane from LDS partials inside
// the score phase; final combine folded into the cosine phase.
// ---------------------------------------------------------------------------
__global__ __launch_bounds__(256, 6) void softmax_attn_cos_kernel(
    const int* __restrict__ ids_a, const int* __restrict__ mask_a,
    const int* __restrict__ ids_b, const int* __restrict__ mask_b,
    const __half* __restrict__ mu_table, const __half* __restrict__ feat_table,
    float* __restrict__ out)
{
    __shared__ int    s_ids[2][LL];
    __shared__ float  s_msk[2][LL];
    __shared__ float4 s_qp[2][2][16];   // q partials (flattened order == column order)
    __shared__ float  s_sc[2][LL];
    __shared__ float4 s_op[2][2][16];   // output partials (same layout)
    __shared__ float  s_sum[2];

    const int tid  = threadIdx.x;
    const int lane = tid & 63;
    const int wave = tid >> 6;        // 0..3
    const int side = wave >> 1;       // 0: a, 1: b
    const int wsub = wave & 1;        // which half of the 128 rows
    const int r8   = lane >> 3;       // 0..7 row subgroup
    const int c8   = lane & 7;        // 16-B chunk (8 halves) within a row
    const int b    = blockIdx.x;

    // ---- phase 1: ids + masks for both sides ----
    {
        const int si = tid >> 7;
        const int l  = tid & 127;
        const int* idp = si ? ids_b  : ids_a;
        const int* mp  = si ? mask_b : mask_a;
        s_ids[si][l] = idp[b * LL + l];
        s_msk[si][l] = (float)mp[b * LL + l];
    }
    __syncthreads();

    // ---- in-wave mask stats (redundant per wave -> no extra phase/barrier) ----
    float mv = s_msk[side][lane] + s_msk[side][lane + 64];
    #pragma unroll
    for (int off = 32; off; off >>= 1) mv += __shfl_xor(mv, off, 64);
    const float denom = fmaxf(mv, 1.0f);
    const bool  allm  = (mv < 0.5f);

    // ---- phase 2: gather unmasked mu rows (8 rows/instr) + q partials ----
    uint4 v[8];
    unsigned kept = 0;
    {
        float4 qa = make_float4(0.f, 0.f, 0.f, 0.f);
        float4 qb = make_float4(0.f, 0.f, 0.f, 0.f);
        #pragma unroll
        for (int it = 0; it < 8; ++it) {
            const int r = wsub * 64 + it * 8 + r8;
            if (s_msk[side][r] > 0.5f) {
                kept |= (1u << it);
                v[it] = ((const uint4*)(mu_table + (size_t)s_ids[side][r] * DD))[c8];
                const float2 f0 = cvt2(v[it].x), f1 = cvt2(v[it].y);
                const float2 f2 = cvt2(v[it].z), f3 = cvt2(v[it].w);
                qa.x += f0.x; qa.y += f0.y; qa.z += f1.x; qa.w += f1.y;
                qb.x += f2.x; qb.y += f2.y; qb.z += f3.x; qb.w += f3.y;
            } else {
                v[it] = make_uint4(0u, 0u, 0u, 0u);
            }
        }
        #pragma unroll
        for (int off = 8; off <= 32; off <<= 1) {   // sum the 8 row-groups
            qa.x += __shfl_xor(qa.x, off, 64); qa.y += __shfl_xor(qa.y, off, 64);
            qa.z += __shfl_xor(qa.z, off, 64); qa.w += __shfl_xor(qa.w, off, 64);
            qb.x += __shfl_xor(qb.x, off, 64); qb.y += __shfl_xor(qb.y, off, 64);
            qb.z += __shfl_xor(qb.z, off, 64); qb.w += __shfl_xor(qb.w, off, 64);
        }
        if (lane < 8) {
            s_qp[side][wsub][2 * c8]     = qa;
            s_qp[side][wsub][2 * c8 + 1] = qb;
        }
    }
    __syncthreads();

    // ---- phase 3: q rebuilt per-lane from partials; scores (v_dot2);
    //      feat prefetched into v[] predicated on kept/allm ----
    {
        const float rd = 1.0f / denom;
        const float4 p00 = s_qp[side][0][2 * c8], p01 = s_qp[side][0][2 * c8 + 1];
        const float4 p10 = s_qp[side][1][2 * c8], p11 = s_qp[side][1][2 * c8 + 1];
        uint4 qq;
        qq.x = pack_h2((p00.x + p10.x) * rd, (p00.y + p10.y) * rd);
        qq.y = pack_h2((p00.z + p10.z) * rd, (p00.w + p10.w) * rd);
        qq.z = pack_h2((p01.x + p11.x) * rd, (p01.y + p11.y) * rd);
        qq.w = pack_h2((p01.z + p11.z) * rd, (p01.w + p11.w) * rd);

        #pragma unroll
        for (int it = 0; it < 8; ++it) {
            const int r = wsub * 64 + it * 8 + r8;
            float p = dot2acc(v[it].x, qq.x, 0.f);
            p = dot2acc(v[it].y, qq.y, p);
            p = dot2acc(v[it].z, qq.z, p);
            p = dot2acc(v[it].w, qq.w, p);
            // feat prefetch (mask-skipped; consumed in phase 5 after the barrier)
            uint4 nf = make_uint4(0u, 0u, 0u, 0u);
            if (allm || ((kept >> it) & 1u))
                nf = ((const uint4*)(feat_table + (size_t)s_ids[side][r] * DD))[c8];
            #pragma unroll
            for (int off = 1; off <= 4; off <<= 1)
                p += __shfl_xor(p, off, 64);         // reduce within 8-lane group
            if (c8 == 0) s_sc[side][r] = ((kept >> it) & 1u) ? p : -1e9f;
            v[it] = nf;
        }
    }
    __syncthreads();

    // ---- phase 4: softmax per side (waves with wsub==0) ----
    if (wsub == 0) {
        const float s1 = s_sc[side][lane], s2 = s_sc[side][lane + 64];
        float mx = fmaxf(s1, s2);
        #pragma unroll
        for (int off = 32; off; off >>= 1) mx = fmaxf(mx, __shfl_xor(mx, off, 64));
        const float e1 = expf(s1 - mx), e2 = expf(s2 - mx);
        s_sc[side][lane] = e1; s_sc[side][lane + 64] = e2;
        float sm = e1 + e2;
        #pragma unroll
        for (int off = 32; off; off >>= 1) sm += __shfl_xor(sm, off, 64);
        if (lane == 0) s_sum[side] = sm;
    }
    __syncthreads();

    // ---- phase 5: attn-weighted sum from held feat regs ----
    {
        float4 oa = make_float4(0.f, 0.f, 0.f, 0.f);
        float4 ob = make_float4(0.f, 0.f, 0.f, 0.f);
        #pragma unroll
        for (int it = 0; it < 8; ++it) {
            const int r = wsub * 64 + it * 8 + r8;
            const float w = s_sc[side][r];   // 0 for masked rows; 1 if all-masked
            const float2 f0 = cvt2(v[it].x), f1 = cvt2(v[it].y);
            const float2 f2 = cvt2(v[it].z), f3 = cvt2(v[it].w);
            oa.x = fmaf(f0.x, w, oa.x); oa.y = fmaf(f0.y, w, oa.y);
            oa.z = fmaf(f1.x, w, oa.z); oa.w = fmaf(f1.y, w, oa.w);
            ob.x = fmaf(f2.x, w, ob.x); ob.y = fmaf(f2.y, w, ob.y);
            ob.z = fmaf(f3.x, w, ob.z); ob.w = fmaf(f3.y, w, ob.w);
        }
        #pragma unroll
        for (int off = 8; off <= 32; off <<= 1) {
            oa.x += __shfl_xor(oa.x, off, 64); oa.y += __shfl_xor(oa.y, off, 64);
            oa.z += __shfl_xor(oa.z, off, 64); oa.w += __shfl_xor(oa.w, off, 64);
            ob.x += __shfl_xor(ob.x, off, 64); ob.y += __shfl_xor(ob.y, off, 64);
            ob.z += __shfl_xor(ob.z, off, 64); ob.w += __shfl_xor(ob.w, off, 64);
        }
        if (lane < 8) {
            s_op[side][wsub][2 * c8]     = oa;
            s_op[side][wsub][2 * c8 + 1] = ob;
        }
    }
    __syncthreads();

    // ---- final: combine partials + cosine, all in wave 0 ----
    if (tid < 64) {
        const float inva = 1.0f / s_sum[0];
        const float invb = 1.0f / s_sum[1];
        // flattened float order of s_op[si][ws] equals column order
        const float* pa0 = (const float*)&s_op[0][0][0];
        const float* pa1 = (const float*)&s_op[0][1][0];
        const float* pb0 = (const float*)&s_op[1][0][0];
        const float* pb1 = (const float*)&s_op[1][1][0];
        const float a = (pa0[tid] + pa1[tid]) * inva;
        const float c = (pb0[tid] + pb1[tid]) * invb;
        float dt = a * c, na = a * a, nb = c * c;
        #pragma unroll
        for (int off = 32; off; off >>= 1) {
            dt += __shfl_xor(dt, off, 64);
            na += __shfl_xor(na, off, 64);
            nb += __shfl_xor(nb, off, 64);
        }
        if (tid == 0) {
            const float dn = fmaxf(sqrtf(na), 1e-8f) * fmaxf(sqrtf(nb), 1e-8f);
            out[b] = 5.0f * dt / dn;
        }
    }
}

extern "C" void kernel_launch(void* const* d_in, const int* in_sizes, int n_in,
                              void* d_out, int out_size, void* d_ws, size_t ws_size,
                              hipStream_t stream) {
    const int*   ids_a  = (const int*)d_in[0];
    const int*   mask_a = (const int*)d_in[1];
    const int*   ids_b  = (const int*)d_in[2];
    const int*   mask_b = (const int*)d_in[3];
    const float* mu     = (const float*)d_in[4];
    const float* feat   = (const float*)d_in[5];
    float* out = (float*)d_out;

    __half* ws_mu   = (__half*)d_ws;
    __half* ws_feat = ws_mu + TAB_ELEMS;   // needs 2*TAB_ELEMS*2 B ~ 12.3 MB of ws

    convert_tables_kernel<<<1024, 256, 0, stream>>>(mu, feat, ws_mu, ws_feat);
    softmax_attn_cos_kernel<<<BB, 256, 0, stream>>>(
        ids_a, mask_a, ids_b, mask_b, ws_mu, ws_feat, out);
}

// Round 12
// 113.971 us; speedup vs baseline: 1.0106x; 1.0106x over previous
//
#include <hip/hip_runtime.h>
#include <hip/hip_fp16.h>
#include <math.h>

// Problem constants (match reference)
#define BB 4096
#define LL 128
#define DD 64
#define VV 50257
#define TAB_ELEMS (VV * DD)   // 3,216,448 per table

typedef _Float16 h2_t __attribute__((ext_vector_type(2)));

// fp16x2 dot-accumulate: one v_dot2_f32_f16 where available.
__device__ __forceinline__ float dot2acc(unsigned a, unsigned b, float c) {
#if __has_builtin(__builtin_amdgcn_fdot2)
    return __builtin_amdgcn_fdot2(__builtin_bit_cast(h2_t, a),
                                  __builtin_bit_cast(h2_t, b), c, false);
#else
    const float2 fa = __half22float2(*(const __half2*)&a);
    const float2 fb = __half22float2(*(const __half2*)&b);
    return fmaf(fa.x, fb.x, fmaf(fa.y, fb.y, c));
#endif
}

__device__ __forceinline__ float2 cvt2(unsigned raw) {
    return __half22float2(*(const __half2*)&raw);
}

__device__ __forceinline__ unsigned pack_h2(float a, float b) {
    union { __half2 h; unsigned u; } p;
    p.h = __floats2half2_rn(a, b);
    return p.u;
}

// ---------------------------------------------------------------------------
// Kernel 1: stream-convert both fp32 tables to fp16 in workspace.
// ---------------------------------------------------------------------------
__global__ __launch_bounds__(256) void convert_tables_kernel(
    const float* __restrict__ mu, const float* __restrict__ feat,
    __half* __restrict__ out_mu, __half* __restrict__ out_feat)
{
    const int n4 = TAB_ELEMS / 4;
    for (int i = blockIdx.x * blockDim.x + threadIdx.x; i < n4;
         i += gridDim.x * blockDim.x) {
        const float4 m = ((const float4*)mu)[i];
        const float4 f = ((const float4*)feat)[i];
        uint2 pm, pf;
        pm.x = pack_h2(m.x, m.y); pm.y = pack_h2(m.z, m.w);
        pf.x = pack_h2(f.x, f.y); pf.y = pack_h2(f.z, f.w);
        ((uint2*)out_mu)[i]   = pm;
        ((uint2*)out_feat)[i] = pf;
    }
}

// ---------------------------------------------------------------------------
// Kernel 2: exact R10 skeleton (best so far) with per-wave op cuts:
//  - kept mask via ONE ballot of this wave's 64 rows (replaces 8 per-iter
//    s_msk LDS reads + compares in phase 2)
//  - byte offsets voff[it] precomputed in phase 2, reused for the feat
//    prefetch (kills phase-3 s_ids LDS reads + address chains; the barrier
//    blocks compiler CSE across phases)
//  - feat loads unconditional (also handles the all-masked case naturally:
//    softmax of all -1e9 -> uniform weights, matching jax)
// ---------------------------------------------------------------------------
__global__ __launch_bounds__(256, 6) void softmax_attn_cos_kernel(
    const int* __restrict__ ids_a, const int* __restrict__ mask_a,
    const int* __restrict__ ids_b, const int* __restrict__ mask_b,
    const __half* __restrict__ mu_table, const __half* __restrict__ feat_table,
    float* __restrict__ out)
{
    __shared__ int      s_ids[2][LL];
    __shared__ float    s_msk[2][LL];
    __shared__ unsigned s_qh[2][32];      // q packed as 32 half2
    __shared__ float4   s_qp[2][2][16];   // q partials
    __shared__ float    s_sc[2][LL];
    __shared__ float4   s_op[2][2][16];
    __shared__ float    s_mean[2][DD];
    __shared__ float    s_sum[2];

    const int tid  = threadIdx.x;
    const int lane = tid & 63;
    const int wave = tid >> 6;        // 0..3
    const int side = wave >> 1;       // 0: a, 1: b
    const int wsub = wave & 1;        // which half of the 128 rows
    const int r8   = lane >> 3;       // 0..7 row subgroup
    const int c8   = lane & 7;        // 16-B chunk (8 halves) within a row
    const int b    = blockIdx.x;

    // ---- phase 1: ids + masks for both sides ----
    {
        const int si = tid >> 7;
        const int l  = tid & 127;
        const int* idp = si ? ids_b  : ids_a;
        const int* mp  = si ? mask_b : mask_a;
        s_ids[si][l] = idp[b * LL + l];
        s_msk[si][l] = (float)mp[b * LL + l];
    }
    __syncthreads();

    // ---- one ballot: bit l of `bal` = mask of row (wsub*64 + l) ----
    const unsigned long long bal =
        __ballot(s_msk[side][wsub * 64 + lane] > 0.5f);

    // ---- phase 2: gather unmasked mu rows (8 rows/instr) + q partials;
    //      precompute byte offsets for reuse in the feat pass ----
    uint4 v[8];
    unsigned voff[8];
    unsigned kept = 0;
    {
        float4 qa = make_float4(0.f, 0.f, 0.f, 0.f);
        float4 qb = make_float4(0.f, 0.f, 0.f, 0.f);
        #pragma unroll
        for (int it = 0; it < 8; ++it) {
            const int r = wsub * 64 + it * 8 + r8;
            voff[it] = ((unsigned)s_ids[side][r] << 7) + ((unsigned)c8 << 4);
            v[it] = make_uint4(0u, 0u, 0u, 0u);
            if ((bal >> (it * 8 + r8)) & 1ull) {
                kept |= (1u << it);
                v[it] = *(const uint4*)((const char*)mu_table + voff[it]);
                const float2 f0 = cvt2(v[it].x), f1 = cvt2(v[it].y);
                const float2 f2 = cvt2(v[it].z), f3 = cvt2(v[it].w);
                qa.x += f0.x; qa.y += f0.y; qa.z += f1.x; qa.w += f1.y;
                qb.x += f2.x; qb.y += f2.y; qb.z += f3.x; qb.w += f3.y;
            }
        }
        #pragma unroll
        for (int off = 8; off <= 32; off <<= 1) {   // sum the 8 row-groups
            qa.x += __shfl_xor(qa.x, off, 64); qa.y += __shfl_xor(qa.y, off, 64);
            qa.z += __shfl_xor(qa.z, off, 64); qa.w += __shfl_xor(qa.w, off, 64);
            qb.x += __shfl_xor(qb.x, off, 64); qb.y += __shfl_xor(qb.y, off, 64);
            qb.z += __shfl_xor(qb.z, off, 64); qb.w += __shfl_xor(qb.w, off, 64);
        }
        if (lane < 8) {
            s_qp[side][wsub][2 * c8]     = qa;
            s_qp[side][wsub][2 * c8 + 1] = qb;
        }
    }
    __syncthreads();

    // ---- q = masked mean (waves 0/1, one per side); store as half2 ----
    if (tid < 128) {
        const int si = tid >> 6;
        const int dd = tid & 63;
        float mv = s_msk[si][dd] + s_msk[si][dd + 64];
        #pragma unroll
        for (int off = 32; off; off >>= 1) mv += __shfl_xor(mv, off, 64);
        const float denom = fmaxf(mv, 1.0f);
        if (dd < 16) {
            const float4 q0 = s_qp[si][0][dd], q1 = s_qp[si][1][dd];
            const float qx = (q0.x + q1.x) / denom, qy = (q0.y + q1.y) / denom;
            const float qz = (q0.z + q1.z) / denom, qw = (q0.w + q1.w) / denom;
            s_qh[si][2 * dd]     = pack_h2(qx, qy);
            s_qh[si][2 * dd + 1] = pack_h2(qz, qw);
        }
    }
    __syncthreads();

    // ---- phase 3: scores from held regs (v_dot2) + prefetch feat into v[]
    //      using the precomputed offsets (no LDS id reads, no addr chains) ----
    {
        const uint4 qq = ((const uint4*)&s_qh[side][0])[c8];  // 8 q cols
        #pragma unroll
        for (int it = 0; it < 8; ++it) {
            const int r = wsub * 64 + it * 8 + r8;
            float p = dot2acc(v[it].x, qq.x, 0.f);
            p = dot2acc(v[it].y, qq.y, p);
            p = dot2acc(v[it].z, qq.z, p);
            p = dot2acc(v[it].w, qq.w, p);
            // unconditional feat prefetch (consumed in phase 5 after barrier)
            const uint4 nf = *(const uint4*)((const char*)feat_table + voff[it]);
            #pragma unroll
            for (int off = 1; off <= 4; off <<= 1)
                p += __shfl_xor(p, off, 64);         // reduce within 8-lane group
            if (c8 == 0) s_sc[side][r] = ((kept >> it) & 1u) ? p : -1e9f;
            v[it] = nf;
        }
    }
    __syncthreads();

    // ---- phase 4: softmax per side (waves with wsub==0) ----
    if (wsub == 0) {
        const float s1 = s_sc[side][lane], s2 = s_sc[side][lane + 64];
        float mx = fmaxf(s1, s2);
        #pragma unroll
        for (int off = 32; off; off >>= 1) mx = fmaxf(mx, __shfl_xor(mx, off, 64));
        const float e1 = expf(s1 - mx), e2 = expf(s2 - mx);
        s_sc[side][lane] = e1; s_sc[side][lane + 64] = e2;
        float sm = e1 + e2;
        #pragma unroll
        for (int off = 32; off; off >>= 1) sm += __shfl_xor(sm, off, 64);
        if (lane == 0) s_sum[side] = sm;
    }
    __syncthreads();

    // ---- phase 5: attn-weighted sum from held feat regs ----
    {
        float4 oa = make_float4(0.f, 0.f, 0.f, 0.f);
        float4 ob = make_float4(0.f, 0.f, 0.f, 0.f);
        #pragma unroll
        for (int it = 0; it < 8; ++it) {
            const int r = wsub * 64 + it * 8 + r8;
            const float w = s_sc[side][r];   // 0 for masked rows; 1 if all-masked
            const float2 f0 = cvt2(v[it].x), f1 = cvt2(v[it].y);
            const float2 f2 = cvt2(v[it].z), f3 = cvt2(v[it].w);
            oa.x = fmaf(f0.x, w, oa.x); oa.y = fmaf(f0.y, w, oa.y);
            oa.z = fmaf(f1.x, w, oa.z); oa.w = fmaf(f1.y, w, oa.w);
            ob.x = fmaf(f2.x, w, ob.x); ob.y = fmaf(f2.y, w, ob.y);
            ob.z = fmaf(f3.x, w, ob.z); ob.w = fmaf(f3.y, w, ob.w);
        }
        #pragma unroll
        for (int off = 8; off <= 32; off <<= 1) {
            oa.x += __shfl_xor(oa.x, off, 64); oa.y += __shfl_xor(oa.y, off, 64);
            oa.z += __shfl_xor(oa.z, off, 64); oa.w += __shfl_xor(oa.w, off, 64);
            ob.x += __shfl_xor(ob.x, off, 64); ob.y += __shfl_xor(ob.y, off, 64);
            ob.z += __shfl_xor(ob.z, off, 64); ob.w += __shfl_xor(ob.w, off, 64);
        }
        if (lane < 8) {
            s_op[side][wsub][2 * c8]     = oa;
            s_op[side][wsub][2 * c8 + 1] = ob;
        }
    }
    __syncthreads();

    // ---- combine halves -> mean vectors ----
    if (tid < 32) {
        const int si = tid >> 4, cc = tid & 15;
        const float inv = 1.0f / s_sum[si];
        const float4 o0 = s_op[si][0][cc], o1 = s_op[si][1][cc];
        float4 o;
        o.x = (o0.x + o1.x) * inv; o.y = (o0.y + o1.y) * inv;
        o.z = (o0.z + o1.z) * inv; o.w = (o0.w + o1.w) * inv;
        ((float4*)&s_mean[si][0])[cc] = o;
    }
    __syncthreads();

    // ---- cosine similarity * 5 (wave 0) ----
    if (tid < 64) {
        const float a = s_mean[0][tid], c = s_mean[1][tid];
        float dt = a * c, na = a * a, nb = c * c;
        #pragma unroll
        for (int off = 32; off; off >>= 1) {
            dt += __shfl_xor(dt, off, 64);
            na += __shfl_xor(na, off, 64);
            nb += __shfl_xor(nb, off, 64);
        }
        if (tid == 0) {
            const float denom = fmaxf(sqrtf(na), 1e-8f) * fmaxf(sqrtf(nb), 1e-8f);
            out[b] = 5.0f * dt / denom;
        }
    }
}

extern "C" void kernel_launch(void* const* d_in, const int* in_sizes, int n_in,
                              void* d_out, int out_size, void* d_ws, size_t ws_size,
                              hipStream_t stream) {
    const int*   ids_a  = (const int*)d_in[0];
    const int*   mask_a = (const int*)d_in[1];
    const int*   ids_b  = (const int*)d_in[2];
    const int*   mask_b = (const int*)d_in[3];
    const float* mu     = (const float*)d_in[4];
    const float* feat   = (const float*)d_in[5];
    float* out = (float*)d_out;

    __half* ws_mu   = (__half*)d_ws;
    __half* ws_feat = ws_mu + TAB_ELEMS;   // needs 2*TAB_ELEMS*2 B ~ 12.3 MB of ws

    convert_tables_kernel<<<2048, 256, 0, stream>>>(mu, feat, ws_mu, ws_feat);
    softmax_attn_cos_kernel<<<BB, 256, 0, stream>>>(
        ids_a, mask_a, ids_b, mask_b, ws_mu, ws_feat, out);
}

// Round 13
// 109.102 us; speedup vs baseline: 1.0557x; 1.0446x over previous
//
#include <hip/hip_runtime.h>
#include <hip/hip_fp16.h>
#include <math.h>

// Problem constants (match reference)
#define BB 4096
#define LL 128
#define DD 64
#define VV 50257
#define TAB_ELEMS (VV * DD)   // 3,216,448 per table

typedef _Float16 h2_t __attribute__((ext_vector_type(2)));

// fp16x2 dot-accumulate: one v_dot2_f32_f16 where available.
__device__ __forceinline__ float dot2acc(unsigned a, unsigned b, float c) {
#if __has_builtin(__builtin_amdgcn_fdot2)
    return __builtin_amdgcn_fdot2(__builtin_bit_cast(h2_t, a),
                                  __builtin_bit_cast(h2_t, b), c, false);
#else
    const float2 fa = __half22float2(*(const __half2*)&a);
    const float2 fb = __half22float2(*(const __half2*)&b);
    return fmaf(fa.x, fb.x, fmaf(fa.y, fb.y, c));
#endif
}

__device__ __forceinline__ float2 cvt2(unsigned raw) {
    return __half22float2(*(const __half2*)&raw);
}

__device__ __forceinline__ unsigned pack_h2(float a, float b) {
    union { __half2 h; unsigned u; } p;
    p.h = __floats2half2_rn(a, b);
    return p.u;
}

// ---------------------------------------------------------------------------
// Kernel 1: stream-convert both fp32 tables to fp16 in workspace.
// ---------------------------------------------------------------------------
__global__ __launch_bounds__(256) void convert_tables_kernel(
    const float* __restrict__ mu, const float* __restrict__ feat,
    __half* __restrict__ out_mu, __half* __restrict__ out_feat)
{
    const int n4 = TAB_ELEMS / 4;
    for (int i = blockIdx.x * blockDim.x + threadIdx.x; i < n4;
         i += gridDim.x * blockDim.x) {
        const float4 m = ((const float4*)mu)[i];
        const float4 f = ((const float4*)feat)[i];
        uint2 pm, pf;
        pm.x = pack_h2(m.x, m.y); pm.y = pack_h2(m.z, m.w);
        pf.x = pack_h2(f.x, f.y); pf.y = pack_h2(f.z, f.w);
        ((uint2*)out_mu)[i]   = pm;
        ((uint2*)out_feat)[i] = pf;
    }
}

// ---------------------------------------------------------------------------
// Kernel 2: R10 skeleton + MASK COMPACTION. Unmasked row ids are compacted
// into s_cid[side][0..nm) via ballot+rank; gather loops run over
// G = ceil(nm/8) groups with wave-uniform skip branches, so EXECUTED gather
// instructions drop ~2x on random 50% masks (predication never did this).
// All compacted rows are live -> no -1e9 in scores except softmax padding.
// All-masked side: nme=128, list=all ids, q=0 -> uniform softmax (exact ref).
// ---------------------------------------------------------------------------
__global__ __launch_bounds__(256, 6) void softmax_attn_cos_kernel(
    const int* __restrict__ ids_a, const int* __restrict__ mask_a,
    const int* __restrict__ ids_b, const int* __restrict__ mask_b,
    const __half* __restrict__ mu_table, const __half* __restrict__ feat_table,
    float* __restrict__ out)
{
    __shared__ int      s_cid[2][LL];     // compacted unmasked ids
    __shared__ int      s_cnt[2][2];      // per-side, per-half unmasked counts
    __shared__ unsigned s_qh[2][32];      // q packed as 32 half2
    __shared__ float4   s_qp[2][2][16];   // q partials
    __shared__ float    s_sc[2][LL];      // scores -> exp weights (compacted)
    __shared__ float4   s_op[2][2][16];
    __shared__ float    s_mean[2][DD];
    __shared__ float    s_sum[2];

    const int tid  = threadIdx.x;
    const int lane = tid & 63;
    const int wave = tid >> 6;        // 0..3
    const int side = wave >> 1;       // 0: a, 1: b
    const int wsub = wave & 1;        // which half (rows / groups parity)
    const int r8   = lane >> 3;       // 0..7 row subgroup
    const int c8   = lane & 7;        // 16-B chunk (8 halves) within a row
    const int b    = blockIdx.x;

    // ---- phase 1: load this wave's 64 rows; ballot-compact within wave ----
    {
        const int l = wsub * 64 + lane;
        const int* idp = side ? ids_b  : ids_a;
        const int* mp  = side ? mask_b : mask_a;
        const int id = idp[b * LL + l];
        const int m  = mp[b * LL + l];
        const unsigned long long bal = __ballot(m != 0);
        if (lane == 0) s_cnt[side][wsub] = __popcll(bal);
        const int rank = __popcll(bal & ((1ull << lane) - 1ull));
        __syncthreads();
        const int offset = wsub ? s_cnt[side][0] : 0;
        if (m) s_cid[side][offset + rank] = id;
        if (s_cnt[side][0] + s_cnt[side][1] == 0)
            s_cid[side][l] = id;                   // all-masked fallback
    }
    __syncthreads();

    const int   nm  = s_cnt[side][0] + s_cnt[side][1];
    const int   nme = (nm == 0) ? 128 : nm;        // effective compacted length
    const int   G   = (nme + 7) >> 3;              // 8-row groups

    // ---- phase 2: gather compacted mu rows (8 rows/instr), q partials;
    //      wave-uniform skip of groups >= G ----
    uint4 v[8];
    unsigned voff[8];
    {
        float4 qa = make_float4(0.f, 0.f, 0.f, 0.f);
        float4 qb = make_float4(0.f, 0.f, 0.f, 0.f);
        #pragma unroll
        for (int it = 0; it < 8; ++it) {
            v[it] = make_uint4(0u, 0u, 0u, 0u);
            voff[it] = 0u;
            const int g = 2 * it + wsub;
            if (g < G) {                            // wave-uniform branch
                const int p = g * 8 + r8;
                const int id = (p < nme) ? s_cid[side][p] : 0;
                voff[it] = ((unsigned)id << 7) + ((unsigned)c8 << 4);
                v[it] = *(const uint4*)((const char*)mu_table + voff[it]);
                if (p < nm) {                       // live rows only (nm==0: none)
                    const float2 f0 = cvt2(v[it].x), f1 = cvt2(v[it].y);
                    const float2 f2 = cvt2(v[it].z), f3 = cvt2(v[it].w);
                    qa.x += f0.x; qa.y += f0.y; qa.z += f1.x; qa.w += f1.y;
                    qb.x += f2.x; qb.y += f2.y; qb.z += f3.x; qb.w += f3.y;
                }
            }
        }
        #pragma unroll
        for (int off = 8; off <= 32; off <<= 1) {   // sum the 8 row-groups
            qa.x += __shfl_xor(qa.x, off, 64); qa.y += __shfl_xor(qa.y, off, 64);
            qa.z += __shfl_xor(qa.z, off, 64); qa.w += __shfl_xor(qa.w, off, 64);
            qb.x += __shfl_xor(qb.x, off, 64); qb.y += __shfl_xor(qb.y, off, 64);
            qb.z += __shfl_xor(qb.z, off, 64); qb.w += __shfl_xor(qb.w, off, 64);
        }
        if (lane < 8) {
            s_qp[side][wsub][2 * c8]     = qa;
            s_qp[side][wsub][2 * c8 + 1] = qb;
        }
    }
    __syncthreads();

    // ---- q = (masked mean) packed as half2; denom from counts ----
    if (tid < 128) {
        const int si = tid >> 6;
        const int dd = tid & 63;
        if (dd < 16) {
            const float dn = fmaxf((float)(s_cnt[si][0] + s_cnt[si][1]), 1.0f);
            const float rd = 1.0f / dn;
            const float4 q0 = s_qp[si][0][dd], q1 = s_qp[si][1][dd];
            s_qh[si][2 * dd]     = pack_h2((q0.x + q1.x) * rd, (q0.y + q1.y) * rd);
            s_qh[si][2 * dd + 1] = pack_h2((q0.z + q1.z) * rd, (q0.w + q1.w) * rd);
        }
    }
    __syncthreads();

    // ---- phase 3: scores from held regs (v_dot2) + feat prefetch,
    //      same wave-uniform group skip ----
    {
        const uint4 qq = ((const uint4*)&s_qh[side][0])[c8];
        #pragma unroll
        for (int it = 0; it < 8; ++it) {
            const int g = 2 * it + wsub;
            if (g < G) {
                const int p = g * 8 + r8;
                float sp = dot2acc(v[it].x, qq.x, 0.f);
                sp = dot2acc(v[it].y, qq.y, sp);
                sp = dot2acc(v[it].z, qq.z, sp);
                sp = dot2acc(v[it].w, qq.w, sp);
                const uint4 nf = *(const uint4*)((const char*)feat_table + voff[it]);
                #pragma unroll
                for (int off = 1; off <= 4; off <<= 1)
                    sp += __shfl_xor(sp, off, 64);   // reduce within 8-lane group
                if (c8 == 0 && p < nme) s_sc[side][p] = sp;
                v[it] = nf;
            }
        }
    }
    __syncthreads();

    // ---- phase 4: softmax over compacted scores (waves with wsub==0) ----
    if (wsub == 0) {
        const float s1 = (lane      < nme) ? s_sc[side][lane]      : -1e9f;
        const float s2 = (lane + 64 < nme) ? s_sc[side][lane + 64] : -1e9f;
        float mx = fmaxf(s1, s2);
        #pragma unroll
        for (int off = 32; off; off >>= 1) mx = fmaxf(mx, __shfl_xor(mx, off, 64));
        const float e1 = expf(s1 - mx), e2 = expf(s2 - mx);   // padding -> 0
        s_sc[side][lane] = e1; s_sc[side][lane + 64] = e2;
        float sm = e1 + e2;
        #pragma unroll
        for (int off = 32; off; off >>= 1) sm += __shfl_xor(sm, off, 64);
        if (lane == 0) s_sum[side] = sm;
    }
    __syncthreads();

    // ---- phase 5: attn-weighted sum from held feat regs ----
    {
        float4 oa = make_float4(0.f, 0.f, 0.f, 0.f);
        float4 ob = make_float4(0.f, 0.f, 0.f, 0.f);
        #pragma unroll
        for (int it = 0; it < 8; ++it) {
            const int g = 2 * it + wsub;
            if (g < G) {
                const int p = g * 8 + r8;
                const float w = (p < nme) ? s_sc[side][p] : 0.f;
                const float2 f0 = cvt2(v[it].x), f1 = cvt2(v[it].y);
                const float2 f2 = cvt2(v[it].z), f3 = cvt2(v[it].w);
                oa.x = fmaf(f0.x, w, oa.x); oa.y = fmaf(f0.y, w, oa.y);
                oa.z = fmaf(f1.x, w, oa.z); oa.w = fmaf(f1.y, w, oa.w);
                ob.x = fmaf(f2.x, w, ob.x); ob.y = fmaf(f2.y, w, ob.y);
                ob.z = fmaf(f3.x, w, ob.z); ob.w = fmaf(f3.y, w, ob.w);
            }
        }
        #pragma unroll
        for (int off = 8; off <= 32; off <<= 1) {
            oa.x += __shfl_xor(oa.x, off, 64); oa.y += __shfl_xor(oa.y, off, 64);
            oa.z += __shfl_xor(oa.z, off, 64); oa.w += __shfl_xor(oa.w, off, 64);
            ob.x += __shfl_xor(ob.x, off, 64); ob.y += __shfl_xor(ob.y, off, 64);
            ob.z += __shfl_xor(ob.z, off, 64); ob.w += __shfl_xor(ob.w, off, 64);
        }
        if (lane < 8) {
            s_op[side][wsub][2 * c8]     = oa;
            s_op[side][wsub][2 * c8 + 1] = ob;
        }
    }
    __syncthreads();

    // ---- combine halves -> mean vectors ----
    if (tid < 32) {
        const int si = tid >> 4, cc = tid & 15;
        const float inv = 1.0f / s_sum[si];
        const float4 o0 = s_op[si][0][cc], o1 = s_op[si][1][cc];
        float4 o;
        o.x = (o0.x + o1.x) * inv; o.y = (o0.y + o1.y) * inv;
        o.z = (o0.z + o1.z) * inv; o.w = (o0.w + o1.w) * inv;
        ((float4*)&s_mean[si][0])[cc] = o;
    }
    __syncthreads();

    // ---- cosine similarity * 5 (wave 0) ----
    if (tid < 64) {
        const float a = s_mean[0][tid], c = s_mean[1][tid];
        float dt = a * c, na = a * a, nb = c * c;
        #pragma unroll
        for (int off = 32; off; off >>= 1) {
            dt += __shfl_xor(dt, off, 64);
            na += __shfl_xor(na, off, 64);
            nb += __shfl_xor(nb, off, 64);
        }
        if (tid == 0) {
            const float denom = fmaxf(sqrtf(na), 1e-8f) * fmaxf(sqrtf(nb), 1e-8f);
            out[b] = 5.0f * dt / denom;
        }
    }
}

extern "C" void kernel_launch(void* const* d_in, const int* in_sizes, int n_in,
                              void* d_out, int out_size, void* d_ws, size_t ws_size,
                              hipStream_t stream) {
    const int*   ids_a  = (const int*)d_in[0];
    const int*   mask_a = (const int*)d_in[1];
    const int*   ids_b  = (const int*)d_in[2];
    const int*   mask_b = (const int*)d_in[3];
    const float* mu     = (const float*)d_in[4];
    const float* feat   = (const float*)d_in[5];
    float* out = (float*)d_out;

    __half* ws_mu   = (__half*)d_ws;
    __half* ws_feat = ws_mu + TAB_ELEMS;   // needs 2*TAB_ELEMS*2 B ~ 12.3 MB of ws

    convert_tables_kernel<<<2048, 256, 0, stream>>>(mu, feat, ws_mu, ws_feat);
    softmax_attn_cos_kernel<<<BB, 256, 0, stream>>>(
        ids_a, mask_a, ids_b, mask_b, ws_mu, ws_feat, out);
}